// Round 11
// baseline (106.577 us; speedup 1.0000x reference)
//
#include <hip/hip_runtime.h>
#include <math.h>

// Time-chunked + warm-up parallelization of a fading-memory recurrence
// pipeline: pre-biquad x2 -> gain/bias -> GRU(H=1) -> post-biquad x2.
// Each thread = (batch, chunk), starting WARMUP steps early with zero states.
// CHUNK=16/WARMUP=12: 28 serial steps/thread, 262144 threads = 4 waves/SIMD.
// Phase-split scheduling (r9, -3.4us): pre-biquads / GRU / post-biquads each
// run over the whole register window; only the GRU keeps a long serial chain.
//
// (1) single kernel -- the knob MLP is BLOCK-UNIFORM (each 256-thread block
// covers 256 chunks of one batch), so it's inlined and runs in the latency
// shadow of the up-front x loads; kills the separate launch.
// (2) WARMUP 16->12: read amplification 2.0x->1.75x; truncation +0.5^12
// ~ 2.4e-4, far below the 2e-3 fast-math floor and 1.3e-2 threshold.

#ifndef CHUNK
#define CHUNK 16
#endif
#ifndef WARMUP
#define WARMUP 12
#endif
#define NWQ ((WARMUP + CHUNK) / 4)   // quads per full window (7)
#define NWUQ (WARMUP / 4)            // warm-up quads (3)
#define NCQ (CHUNK / 4)              // chunk quads (4)

__device__ __forceinline__ float fast_rcp(float x) {
    return __builtin_amdgcn_rcpf(x);
}
__device__ __forceinline__ float fast_exp2(float x) {
    return __builtin_amdgcn_exp2f(x);
}
__device__ __forceinline__ float sigm_fast(float v) {
    return fast_rcp(1.0f + fast_exp2(-1.44269504088896341f * v));
}
__device__ __forceinline__ float tanh_fast(float v) {
    return fmaf(-2.0f, fast_rcp(1.0f + fast_exp2(2.88539008177792681f * v)), 1.0f);
}

__global__ __launch_bounds__(256) void preamp_fused(
    const float* __restrict__ x, const float* __restrict__ knobs,
    const float* __restrict__ pre_c, const float* __restrict__ post_c,
    const float* __restrict__ gw_ih, const float* __restrict__ gw_hh,
    const float* __restrict__ gb_ih, const float* __restrict__ gb_hh,
    const float* __restrict__ gw_out, const float* __restrict__ gb_out,
    const float* __restrict__ kw1, const float* __restrict__ kb1,
    const float* __restrict__ kw2, const float* __restrict__ kb2,
    float* __restrict__ out, int L, int cshift)
{
    const int tid = blockIdx.x * 256 + threadIdx.x;
    const int b = tid >> cshift;               // batch (block-uniform)
    const int c = tid & ((1 << cshift) - 1);   // chunk within batch

    const long base = (long)b * (long)L;
    const float* xp = x + base;
    float* op = out + base;
    const int t0 = c * CHUNK;

    // ---- issue window loads FIRST: HBM latency hides under the knob MLP --
    float4 qb[NWQ];
    if (c != 0) {
        const float* wb = xp + (t0 - WARMUP);
#pragma unroll
        for (int i = 0; i < NWQ; ++i)
            qb[i] = *reinterpret_cast<const float4*>(wb + 4 * i);
    } else {
#pragma unroll
        for (int i = 0; i < NCQ; ++i)
            qb[i] = *reinterpret_cast<const float4*>(xp + 4 * i);
    }

    // ---- knob MLP (block-uniform; runs during load latency) --------------
    const float knob = knobs[b];
    float a0 = kb2[0], a1 = kb2[1];
#pragma unroll
    for (int j = 0; j < 16; ++j) {
        const float hj = tanh_fast(fmaf(knob, kw1[j], kb1[j]));
        a0 = fmaf(hj, kw2[j], a0);
        a1 = fmaf(hj, kw2[16 + j], a1);
    }
    const float p0 = sigm_fast(a0);
    const float p1 = sigm_fast(a1);
    const float gain = fast_exp2(1.44269504088896341f * fmaf(p0, 4.0f, -2.0f));
    const float bias = 0.1f * p1;

    // ---- GRU constants with log2(e) + gain/bias folded -------------------
    const float LOG2E = 1.44269504088896341f;
    const float TWOLOG2E = 2.88539008177792681f;
    const float kr_u = -LOG2E * gw_ih[0];
    const float kz_u = -LOG2E * gw_ih[1];
    const float kn_u = TWOLOG2E * gw_ih[2];
    const float Kry = kr_u * gain;
    const float Krc = fmaf(kr_u, bias, -LOG2E * (gb_ih[0] + gb_hh[0]));
    const float Kzy = kz_u * gain;
    const float Kzc = fmaf(kz_u, bias, -LOG2E * (gb_ih[1] + gb_hh[1]));
    const float Kny = kn_u * gain;
    const float Knc = fmaf(kn_u, bias, TWOLOG2E * gb_ih[2]);
    const float kr_h = -LOG2E * gw_hh[0];
    const float kz_h = -LOG2E * gw_hh[1];
    const float kn_h = TWOLOG2E * gw_hh[2];
    const float kn_c = TWOLOG2E * gb_hh[2];
    const float wo = gw_out[0], bo = gb_out[0];

    // ---- filter coefficients (uniform -> scalar) --------------------------
    const float f0b0 = pre_c[0],  f0b1 = pre_c[1],  f0b2 = pre_c[2];
    const float f0a1 = -pre_c[3], f0a2 = -pre_c[4];
    const float f1b0 = pre_c[5],  f1b1 = pre_c[6],  f1b2 = pre_c[7];
    const float f1a1 = -pre_c[8], f1a2 = -pre_c[9];
    const float f2b0 = post_c[0], f2b1 = post_c[1], f2b2 = post_c[2];
    const float f2a1 = -post_c[3], f2a2 = -post_c[4];
    const float f3b0 = post_c[5], f3b1 = post_c[6], f3b2 = post_c[7];
    const float f3a1 = -post_c[8], f3a2 = -post_c[9];

    // Phase macros: read (io), overwrite with stage output (in-place reuse).
#define PRE_STEP(io)                                                         \
    {                                                                        \
        const float xt = (io);                                               \
        float ff = fmaf(f0b1, ax1, f0b0 * xt);                               \
        ff = fmaf(f0b2, ax2, ff);                                            \
        ff = fmaf(f0a2, ay2, ff);                                            \
        const float y = fmaf(f0a1, ay1, ff);                                 \
        ax2 = ax1; ax1 = xt; ay2 = ay1; ay1 = y;                             \
        float ff1 = fmaf(f1b1, bx1, f1b0 * y);                               \
        ff1 = fmaf(f1b2, bx2, ff1);                                          \
        ff1 = fmaf(f1a2, by2, ff1);                                          \
        const float y2 = fmaf(f1a1, by1, ff1);                               \
        bx2 = bx1; bx1 = y; by2 = by1; by1 = y2;                             \
        (io) = y2;                                                           \
    }
#define GRU_STEP(io)                                                         \
    {                                                                        \
        const float y2 = (io);                                               \
        const float ur = fmaf(Kry, y2, Krc);                                 \
        const float uz = fmaf(Kzy, y2, Kzc);                                 \
        const float un = fmaf(Kny, y2, Knc);                                 \
        const float hn = fmaf(kn_h, h, kn_c);                                \
        const float r = fast_rcp(1.0f + fast_exp2(fmaf(kr_h, h, ur)));       \
        const float z = fast_rcp(1.0f + fast_exp2(fmaf(kz_h, h, uz)));       \
        const float n = fmaf(-2.0f,                                          \
            fast_rcp(1.0f + fast_exp2(fmaf(r, hn, un))), 1.0f);              \
        h = fmaf(z, h - n, n);                                               \
        (io) = fmaf(wo, h, bo);                                              \
    }
#define POST_STEP(io)                                                        \
    {                                                                        \
        const float v = (io);                                                \
        float ff2 = fmaf(f2b1, cx1, f2b0 * v);                               \
        ff2 = fmaf(f2b2, cx2, ff2);                                          \
        ff2 = fmaf(f2a2, cy2, ff2);                                          \
        const float q = fmaf(f2a1, cy1, ff2);                                \
        cx2 = cx1; cx1 = v; cy2 = cy1; cy1 = q;                              \
        float ff3 = fmaf(f3b1, dx1, f3b0 * q);                               \
        ff3 = fmaf(f3b2, dx2, ff3);                                          \
        ff3 = fmaf(f3a2, dy2, ff3);                                          \
        const float q2 = fmaf(f3a1, dy1, ff3);                               \
        dx2 = dx1; dx1 = q; dy2 = dy1; dy1 = q2;                             \
        (io) = q2;                                                           \
    }

    if (c != 0) {
        // phase 1: pre-biquads (x -> y2)
        {
            float ax1 = 0.f, ax2 = 0.f, ay1 = 0.f, ay2 = 0.f;
            float bx1 = 0.f, bx2 = 0.f, by1 = 0.f, by2 = 0.f;
#pragma unroll
            for (int i = 0; i < NWQ; ++i) {
                PRE_STEP(qb[i].x); PRE_STEP(qb[i].y);
                PRE_STEP(qb[i].z); PRE_STEP(qb[i].w);
            }
        }
        // phase 2: GRU (y2 -> v)
        {
            float h = 0.f;
#pragma unroll
            for (int i = 0; i < NWQ; ++i) {
                GRU_STEP(qb[i].x); GRU_STEP(qb[i].y);
                GRU_STEP(qb[i].z); GRU_STEP(qb[i].w);
            }
        }
        // phase 3: post-biquads (v -> q2)
        {
            float cx1 = 0.f, cx2 = 0.f, cy1 = 0.f, cy2 = 0.f;
            float dx1 = 0.f, dx2 = 0.f, dy1 = 0.f, dy2 = 0.f;
#pragma unroll
            for (int i = 0; i < NWQ; ++i) {
                POST_STEP(qb[i].x); POST_STEP(qb[i].y);
                POST_STEP(qb[i].z); POST_STEP(qb[i].w);
            }
        }
        // store chunk half only
#pragma unroll
        for (int i = 0; i < NCQ; ++i)
            *reinterpret_cast<float4*>(op + t0 + 4 * i) = qb[NWUQ + i];
    } else {
        // c == 0: zero states at t=0 are EXACT; no warm-up
        {
            float ax1 = 0.f, ax2 = 0.f, ay1 = 0.f, ay2 = 0.f;
            float bx1 = 0.f, bx2 = 0.f, by1 = 0.f, by2 = 0.f;
#pragma unroll
            for (int i = 0; i < NCQ; ++i) {
                PRE_STEP(qb[i].x); PRE_STEP(qb[i].y);
                PRE_STEP(qb[i].z); PRE_STEP(qb[i].w);
            }
        }
        {
            float h = 0.f;
#pragma unroll
            for (int i = 0; i < NCQ; ++i) {
                GRU_STEP(qb[i].x); GRU_STEP(qb[i].y);
                GRU_STEP(qb[i].z); GRU_STEP(qb[i].w);
            }
        }
        {
            float cx1 = 0.f, cx2 = 0.f, cy1 = 0.f, cy2 = 0.f;
            float dx1 = 0.f, dx2 = 0.f, dy1 = 0.f, dy2 = 0.f;
#pragma unroll
            for (int i = 0; i < NCQ; ++i) {
                POST_STEP(qb[i].x); POST_STEP(qb[i].y);
                POST_STEP(qb[i].z); POST_STEP(qb[i].w);
            }
        }
#pragma unroll
        for (int i = 0; i < NCQ; ++i)
            *reinterpret_cast<float4*>(op + 4 * i) = qb[i];
    }
#undef PRE_STEP
#undef GRU_STEP
#undef POST_STEP
}

extern "C" void kernel_launch(void* const* d_in, const int* in_sizes, int n_in,
                              void* d_out, int out_size, void* d_ws, size_t ws_size,
                              hipStream_t stream) {
    const float* x      = (const float*)d_in[0];
    const float* knobs  = (const float*)d_in[1];
    const float* pre_c  = (const float*)d_in[2];
    const float* post_c = (const float*)d_in[3];
    const float* gw_ih  = (const float*)d_in[4];
    const float* gw_hh  = (const float*)d_in[5];
    const float* gb_ih  = (const float*)d_in[6];
    const float* gb_hh  = (const float*)d_in[7];
    const float* gw_out = (const float*)d_in[8];
    const float* gb_out = (const float*)d_in[9];
    const float* kw1    = (const float*)d_in[10];
    const float* kb1    = (const float*)d_in[11];
    const float* kw2    = (const float*)d_in[12];
    const float* kb2    = (const float*)d_in[13];
    float* out = (float*)d_out;

    const int B = in_sizes[1];                 // 64
    const int L = in_sizes[0] / B;             // 65536
    const int nchunks = L / CHUNK;             // 4096 (power of two)
    int cshift = 0; while ((1 << cshift) < nchunks) ++cshift;
    const int threads = B * nchunks;           // 262144

    preamp_fused<<<dim3(threads / 256), dim3(256), 0, stream>>>(
        x, knobs, pre_c, post_c, gw_ih, gw_hh, gb_ih, gb_hh, gw_out, gb_out,
        kw1, kb1, kw2, kb2, out, L, cshift);
}